// Round 13
// baseline (675.712 us; speedup 1.0000x reference)
//
#include <hip/hip_runtime.h>
#include <math.h>

#define NN 50000
#define NE 800000
#define NB 196        // dst buckets of 256 nodes: (NN+255)>>8

typedef float v4f __attribute__((ext_vector_type(4)));
typedef short v8s __attribute__((ext_vector_type(8)));

__device__ __forceinline__ unsigned short f2bf(float f) {
  unsigned u = __float_as_uint(f);
  u = u + 0x7FFFu + ((u >> 16) & 1u);
  return (unsigned short)(u >> 16);
}
__device__ __forceinline__ float bf2f(unsigned short h) {
  return __uint_as_float(((unsigned)h) << 16);
}

// ================= graph build: two-level bucket sort (dense writes) ==========

__global__ __launch_bounds__(256) void k_bhist(const int* __restrict__ dst,
                                               int* __restrict__ gbcnt) {
  __shared__ int lcnt[NB];
  int t = threadIdx.x;
  for (int i = t; i < NB; i += 256) lcnt[i] = 0;
  __syncthreads();
  int eb = blockIdx.x * 4096;
#pragma unroll
  for (int i = 0; i < 16; ++i) {
    int e = eb + i * 256 + t;
    if (e < NE) atomicAdd(&lcnt[dst[e] >> 8], 1);
  }
  __syncthreads();
  for (int i = t; i < NB; i += 256)
    if (lcnt[i]) atomicAdd(&gbcnt[i], lcnt[i]);
}

__global__ __launch_bounds__(256) void k_bscan(const int* __restrict__ gbcnt,
                                               int* __restrict__ boff,
                                               int* __restrict__ gcur,
                                               int* __restrict__ offs) {
  __shared__ int sd[256];
  int t = threadIdx.x;
  int v = (t < NB) ? gbcnt[t] : 0;
  sd[t] = v;
  __syncthreads();
  for (int o = 1; o < 256; o <<= 1) {
    int u = (t >= o) ? sd[t - o] : 0;
    __syncthreads();
    sd[t] += u;
    __syncthreads();
  }
  if (t < NB) { int x = sd[t] - v; boff[t] = x; gcur[t] = x; }
  if (t == NB - 1) boff[NB] = sd[t];
  if (t == 0) offs[NN] = NE;
}

__global__ __launch_bounds__(256) void k_bscatter(const int* __restrict__ src,
                                                  const int* __restrict__ dst,
                                                  int* __restrict__ gcur,
                                                  unsigned* __restrict__ ebuf) {
  __shared__ int cnt[NB];
  __shared__ int base[NB];
  int t = threadIdx.x;
  for (int i = t; i < NB; i += 256) cnt[i] = 0;
  __syncthreads();
  int eb = blockIdx.x * 4096;
  unsigned pk[16];
  int bk[16], lp[16];
#pragma unroll
  for (int i = 0; i < 16; ++i) {
    int e = eb + i * 256 + t;
    if (e < NE) {
      int d = dst[e];
      int b = d >> 8;
      pk[i] = ((unsigned)src[e] << 8) | (unsigned)(d & 255);
      bk[i] = b;
      lp[i] = atomicAdd(&cnt[b], 1);
    }
  }
  __syncthreads();
  for (int i = t; i < NB; i += 256)
    base[i] = cnt[i] ? atomicAdd(&gcur[i], cnt[i]) : 0;
  __syncthreads();
#pragma unroll
  for (int i = 0; i < 16; ++i) {
    int e = eb + i * 256 + t;
    if (e < NE) ebuf[base[bk[i]] + lp[i]] = pk[i];
  }
}

__global__ __launch_bounds__(256) void k_bbuild(const unsigned* __restrict__ ebuf,
                                                const int* __restrict__ boff,
                                                int* __restrict__ offs,
                                                float* __restrict__ invd,
                                                int* __restrict__ csr) {
  __shared__ int dcnt[256];
  __shared__ int cur[256];
  int t = threadIdx.x;
  int b = blockIdx.x;
  int node0 = b << 8;
  int es = boff[b], ee = boff[b + 1];
  dcnt[t] = 0;
  __syncthreads();
  for (int e = es + t; e < ee; e += 256) atomicAdd(&dcnt[ebuf[e] & 255], 1);
  __syncthreads();
  int v = dcnt[t];
  cur[t] = v;
  __syncthreads();
  for (int o = 1; o < 256; o <<= 1) {
    int u = (t >= o) ? cur[t - o] : 0;
    __syncthreads();
    cur[t] += u;
    __syncthreads();
  }
  int excl = cur[t] - v;
  int node = node0 + t;
  if (node < NN) {
    offs[node] = es + excl;
    invd[node] = 1.0f / fmaxf((float)v, 1.0f);
  }
  __syncthreads();
  cur[t] = es + excl;
  __syncthreads();
  for (int e = es + t; e < ee; e += 256) {
    unsigned pk = ebuf[e];
    int p = atomicAdd(&cur[pk & 255], 1);
    csr[p] = (int)(pk >> 8);
  }
}

// ================= W pre-pack: fragment-ready bf16 hi/lo, gates folded =======
struct WPrepArgs {
  const float* w[15];   // block base (row offset pre-applied), row stride 64
  int gidx[15];         // skip index or -1
  const float* skip;
  unsigned short* wbuf;
};

__global__ __launch_bounds__(256) void k_wprep(WPrepArgs P) {
  int slot = blockIdx.x;
  int t = threadIdx.x;
  const float* w = P.w[slot];
  float gs = 1.0f;
  if (P.gidx[slot] >= 0) gs = 1.0f / (1.0f + __expf(-P.skip[P.gidx[slot]]));
  unsigned short* hi = P.wbuf + (size_t)slot * 8192;
  unsigned short* lo = hi + 4096;
#pragma unroll
  for (int half = 0; half < 2; ++half) {
    int p = t + 256 * half;          // 0..511
    int frag = p >> 6, lane = p & 63;
    int ks = frag >> 2, ct = frag & 3;
    int qd = lane >> 4, ln = lane & 15;
    v8s hv, lv;
#pragma unroll
    for (int j = 0; j < 8; ++j) {
      float f = w[(size_t)(ks * 32 + qd * 8 + j) * 64 + ct * 16 + ln] * gs;
      unsigned short h = f2bf(f);
      hv[j] = (short)h;
      lv[j] = (short)f2bf(f - bf2f(h));
    }
    *(v8s*)(hi + (size_t)p * 8) = hv;
    *(v8s*)(lo + (size_t)p * 8) = lv;
  }
}

// ================= fused pre-MLP: relu(nf@W1+b1)@W2+b2, t0 stays in LDS ======
struct PreArgs {
  const float* nf;       // [n][128] fp32
  const float* b1;
  const float* b2;
  const unsigned short* wbuf;
  unsigned short* outx;  // [n][128] bf16 hi|lo
  float* colsum;         // sv[0:64]
  int n;
};

__global__ __launch_bounds__(1024) void k_pre(PreArgs A) {
  __shared__ unsigned short sm[64 * 136];   // [row][hi 0-63 | lo 64-127 | pad]
  const int t    = threadIdx.x;
  const int wv   = t >> 6;        // 0..15
  const int lane = t & 63;
  const int rb   = wv >> 2, cs = wv & 3;
  const int qd   = lane >> 4, ln = lane & 15;
  const int n0   = blockIdx.x * 64;
  const int arow = n0 + rb * 16 + ln;
  const bool arv = arow < A.n;

  // ---- pass 1: t0-tile = relu(nf @ pre_w1 + b1), slots 0,1 ----
  v4f acc1 = (v4f){0.f, 0.f, 0.f, 0.f};
#pragma unroll
  for (int src = 0; src < 2; ++src) {
    v8s ah[2], al[2];
#pragma unroll
    for (int ks = 0; ks < 2; ++ks) {
      float f[8];
      if (arv) {
        const float* p = A.nf + (size_t)arow * 128 + src * 64 + ks * 32 + qd * 8;
        float4 u0 = *(const float4*)(p);
        float4 u1 = *(const float4*)(p + 4);
        f[0] = u0.x; f[1] = u0.y; f[2] = u0.z; f[3] = u0.w;
        f[4] = u1.x; f[5] = u1.y; f[6] = u1.z; f[7] = u1.w;
      } else {
#pragma unroll
        for (int j = 0; j < 8; ++j) f[j] = 0.f;
      }
      v8s hv, lv;
#pragma unroll
      for (int j = 0; j < 8; ++j) {
        unsigned short h = f2bf(f[j]);
        hv[j] = (short)h;
        lv[j] = (short)f2bf(f[j] - bf2f(h));
      }
      ah[ks] = hv; al[ks] = lv;
    }
    const unsigned short* wb = A.wbuf + (size_t)src * 8192;
#pragma unroll
    for (int ks = 0; ks < 2; ++ks) {
      const unsigned short* fp = wb + (size_t)((ks * 4 + cs) * 64 + lane) * 8;
      v8s bh = *(const v8s*)(fp);
      v8s bl = *(const v8s*)(fp + 4096);
      acc1 = __builtin_amdgcn_mfma_f32_16x16x32_bf16(ah[ks], bh, acc1, 0, 0, 0);
      acc1 = __builtin_amdgcn_mfma_f32_16x16x32_bf16(al[ks], bh, acc1, 0, 0, 0);
      acc1 = __builtin_amdgcn_mfma_f32_16x16x32_bf16(ah[ks], bl, acc1, 0, 0, 0);
    }
  }
  // epilogue 1 -> LDS (C-layout -> row-major split bf16)
  {
    float bv = A.b1[cs * 16 + ln];
#pragma unroll
    for (int r = 0; r < 4; ++r) {
      int row = rb * 16 + qd * 4 + r;
      float v = fmaxf(acc1[r] + bv, 0.f);
      unsigned short h = f2bf(v);
      sm[row * 136 + cs * 16 + ln] = h;
      sm[row * 136 + 64 + cs * 16 + ln] = f2bf(v - bf2f(h));
    }
  }
  __syncthreads();

  // ---- pass 2: x-tile = t0 @ pre_w2 + b2 (slot 2), colsum ----
  v4f acc2 = (v4f){0.f, 0.f, 0.f, 0.f};
  {
    const unsigned short* p = sm + (size_t)(rb * 16 + ln) * 136 + qd * 8;
    v8s ah0 = *(const v8s*)(p);
    v8s al0 = *(const v8s*)(p + 64);
    v8s ah1 = *(const v8s*)(p + 32);
    v8s al1 = *(const v8s*)(p + 96);
    const unsigned short* wb = A.wbuf + (size_t)2 * 8192;
#pragma unroll
    for (int ks = 0; ks < 2; ++ks) {
      const unsigned short* fp = wb + (size_t)((ks * 4 + cs) * 64 + lane) * 8;
      v8s bh = *(const v8s*)(fp);
      v8s bl = *(const v8s*)(fp + 4096);
      v8s ah = ks ? ah1 : ah0, al = ks ? al1 : al0;
      acc2 = __builtin_amdgcn_mfma_f32_16x16x32_bf16(ah, bh, acc2, 0, 0, 0);
      acc2 = __builtin_amdgcn_mfma_f32_16x16x32_bf16(al, bh, acc2, 0, 0, 0);
      acc2 = __builtin_amdgcn_mfma_f32_16x16x32_bf16(ah, bl, acc2, 0, 0, 0);
    }
  }
  float cv = 0.f;
  float bv = A.b2[cs * 16 + ln];
#pragma unroll
  for (int r = 0; r < 4; ++r) {
    int node = n0 + rb * 16 + qd * 4 + r;
    if (node >= A.n) continue;
    float v = acc2[r] + bv;          // no relu on x
    unsigned short h = f2bf(v);
    A.outx[(size_t)node * 128 + cs * 16 + ln] = h;
    A.outx[(size_t)node * 128 + 64 + cs * 16 + ln] = f2bf(v - bf2f(h));
    cv += v;
  }
  cv += __shfl_xor(cv, 16, 64);
  cv += __shfl_xor(cv, 32, 64);
  if (qd == 0) atomicAdd(&A.colsum[cs * 16 + ln], cv);
}

// ================= fused aggregate + multi-source linear =====================
// Phase 1 (16 waves x 4 nodes): gather-mean neighbors of this block's 64 nodes
// from gfeat into LDS (split bf16, padded rows); optionally write mean to global
// for later layers. One barrier. Phase 2: per-wave 16x16 MFMA tile
// (wave = row-block x col-slice); source 0 = LDS mean, rest = global bf16 rows
// (register-prefetched). Output relu'd + fused colsum.
struct LayerArgs {
  const unsigned short* gfeat;       // gather source (prev embedding, [n][128])
  const int* offs; const int* csr; const float* invd;
  unsigned short* mean_out;          // [n][128] global mean, or nullptr
  const unsigned short* asrc[6];     // asrc[0] unused (LDS mean)
  int wslot[6];
  int nsrc;
  const float* bias;
  const unsigned short* wbuf;
  unsigned short* outp;              // [n][128]
  float* colsum;
  int n;
};

__global__ __launch_bounds__(1024) void k_layer(LayerArgs A) {
  __shared__ unsigned short sm[64 * 136];
  const int t    = threadIdx.x;
  const int wv   = t >> 6;
  const int lane = t & 63;
  const int n0   = blockIdx.x * 64;

  // ---- phase 1: aggregate (wave per node, 4 nodes serial) ----
  {
    const int nsub = lane >> 4, cg = lane & 15;
    for (int g = 0; g < 4; ++g) {
      const int row = wv * 4 + g;
      const int node = n0 + row;
      float a[8];
#pragma unroll
      for (int i = 0; i < 8; ++i) a[i] = 0.f;
      if (node < A.n) {
        int s = A.offs[node], e = A.offs[node + 1];
        if (e > s) {
          int emax = e - 1;
          for (int p0 = s; p0 < e; p0 += 16) {
            int pa = p0 + nsub, pb = p0 + 4 + nsub, pc = p0 + 8 + nsub, pd = p0 + 12 + nsub;
            int ja = A.csr[pa < emax ? pa : emax];
            int jb = A.csr[pb < emax ? pb : emax];
            int jc = A.csr[pc < emax ? pc : emax];
            int jd = A.csr[pd < emax ? pd : emax];
            v8s va = *(const v8s*)(A.gfeat + (size_t)ja * 128 + cg * 8);
            v8s vb = *(const v8s*)(A.gfeat + (size_t)jb * 128 + cg * 8);
            v8s vc = *(const v8s*)(A.gfeat + (size_t)jc * 128 + cg * 8);
            v8s vd = *(const v8s*)(A.gfeat + (size_t)jd * 128 + cg * 8);
            if (pa < e) {
#pragma unroll
              for (int i = 0; i < 8; ++i) a[i] += bf2f((unsigned short)va[i]);
            }
            if (pb < e) {
#pragma unroll
              for (int i = 0; i < 8; ++i) a[i] += bf2f((unsigned short)vb[i]);
            }
            if (pc < e) {
#pragma unroll
              for (int i = 0; i < 8; ++i) a[i] += bf2f((unsigned short)vc[i]);
            }
            if (pd < e) {
#pragma unroll
              for (int i = 0; i < 8; ++i) a[i] += bf2f((unsigned short)vd[i]);
            }
          }
        }
      }
#pragma unroll
      for (int i = 0; i < 8; ++i) {
        a[i] += __shfl_xor(a[i], 8, 64);   // hi + lo plane
        a[i] += __shfl_xor(a[i], 16, 64);  // neighbor slots
        a[i] += __shfl_xor(a[i], 32, 64);
      }
      if (lane < 8) {
        float d = (node < A.n) ? A.invd[node] : 0.f;
        v8s oh, ol;
#pragma unroll
        for (int i = 0; i < 8; ++i) {
          float m = a[i] * d;
          unsigned short h = f2bf(m);
          oh[i] = (short)h;
          ol[i] = (short)f2bf(m - bf2f(h));
        }
        *(v8s*)(sm + (size_t)row * 136 + lane * 8) = oh;
        *(v8s*)(sm + (size_t)row * 136 + 64 + lane * 8) = ol;
        if (A.mean_out && node < A.n) {
          *(v8s*)(A.mean_out + (size_t)node * 128 + lane * 8) = oh;
          *(v8s*)(A.mean_out + (size_t)node * 128 + 64 + lane * 8) = ol;
        }
      }
    }
  }
  __syncthreads();

  // ---- phase 2: MFMA ----
  const int rb = wv >> 2, cs = wv & 3;
  const int qd = lane >> 4, ln = lane & 15;
  v4f acc = (v4f){0.f, 0.f, 0.f, 0.f};
  const int arow = n0 + rb * 16 + ln;
  const bool arv = arow < A.n;

  v8s curh[2], curl[2], rawh[2], rawl[2];
  {  // source 0 = LDS mean
    const unsigned short* p = sm + (size_t)(rb * 16 + ln) * 136 + qd * 8;
    curh[0] = *(const v8s*)(p);
    curl[0] = *(const v8s*)(p + 64);
    curh[1] = *(const v8s*)(p + 32);
    curl[1] = *(const v8s*)(p + 96);
  }
  auto loadG = [&](int s) {
    if (arv) {
      const unsigned short* ph = A.asrc[s] + (size_t)arow * 128;
#pragma unroll
      for (int ks = 0; ks < 2; ++ks) {
        rawh[ks] = *(const v8s*)(ph + ks * 32 + qd * 8);
        rawl[ks] = *(const v8s*)(ph + 64 + ks * 32 + qd * 8);
      }
    } else {
      v8s z;
#pragma unroll
      for (int j = 0; j < 8; ++j) z[j] = 0;
      rawh[0] = rawh[1] = rawl[0] = rawl[1] = z;
    }
  };

  for (int s = 0; s < A.nsrc; ++s) {
    if (s + 1 < A.nsrc) loadG(s + 1);          // prefetch next source
    const unsigned short* wb = A.wbuf + (size_t)A.wslot[s] * 8192;
#pragma unroll
    for (int ks = 0; ks < 2; ++ks) {
      const unsigned short* fp = wb + (size_t)((ks * 4 + cs) * 64 + lane) * 8;
      v8s bh = *(const v8s*)(fp);
      v8s bl = *(const v8s*)(fp + 4096);
      acc = __builtin_amdgcn_mfma_f32_16x16x32_bf16(curh[ks], bh, acc, 0, 0, 0);
      acc = __builtin_amdgcn_mfma_f32_16x16x32_bf16(curl[ks], bh, acc, 0, 0, 0);
      acc = __builtin_amdgcn_mfma_f32_16x16x32_bf16(curh[ks], bl, acc, 0, 0, 0);
    }
    if (s + 1 < A.nsrc) {
      curh[0] = rawh[0]; curh[1] = rawh[1];
      curl[0] = rawl[0]; curl[1] = rawl[1];
    }
  }

  // ---- epilogue: bias+relu, write planes, colsum ----
  float cv = 0.f;
  float bv = A.bias[cs * 16 + ln];
#pragma unroll
  for (int r = 0; r < 4; ++r) {
    int node = n0 + rb * 16 + qd * 4 + r;   // C/D: row=(lane>>4)*4+reg, col=lane&15
    if (node >= A.n) continue;
    float v = fmaxf(acc[r] + bv, 0.f);
    unsigned short h = f2bf(v);
    A.outp[(size_t)node * 128 + cs * 16 + ln] = h;
    A.outp[(size_t)node * 128 + 64 + cs * 16 + ln] = f2bf(v - bf2f(h));
    cv += v;
  }
  cv += __shfl_xor(cv, 16, 64);
  cv += __shfl_xor(cv, 32, 64);
  if (qd == 0) atomicAdd(&A.colsum[cs * 16 + ln], cv);
}

// ---------------- tiny post-MLP (single block) ----------------
__global__ __launch_bounds__(256) void k_post(const float* __restrict__ s,
                                              const float* __restrict__ w1, const float* __restrict__ b1,
                                              const float* __restrict__ w2, const float* __restrict__ b2,
                                              const float* __restrict__ w3, const float* __restrict__ b3,
                                              const float* __restrict__ w4, const float* __restrict__ b4,
                                              float* __restrict__ outp) {
  __shared__ float sh[256], h1[64], h2[64], h3[256];
  int t = threadIdx.x;
  sh[t] = s[t];
  __syncthreads();
  if (t < 64) {
    float a = b1[t];
    for (int k = 0; k < 256; ++k) a += sh[k] * w1[k * 64 + t];
    h1[t] = (a >= 0.f) ? a : 0.1f * a;   // leaky_relu 0.1
  }
  __syncthreads();
  if (t < 64) {
    float a = b2[t];
    for (int k = 0; k < 64; ++k) a += h1[k] * w2[k * 64 + t];
    h2[t] = fmaxf(a, 0.f);
  }
  __syncthreads();
  {
    float a = b3[t];
    for (int k = 0; k < 64; ++k) a += h2[k] * w3[k * 256 + t];
    h3[t] = fmaxf(a, 0.f);
  }
  __syncthreads();
  if (t < 64) {
    float a = b4[t];
    for (int k = 0; k < 256; ++k) a += h3[k] * w4[k * 64 + t];
    outp[t] = a;
  }
}

extern "C" void kernel_launch(void* const* d_in, const int* in_sizes, int n_in,
                              void* d_out, int out_size, void* d_ws, size_t ws_size,
                              hipStream_t stream) {
  const float* nf     = (const float*)d_in[0];
  const int*   ei     = (const int*)d_in[1];
  const float* pre_w1 = (const float*)d_in[2];
  const float* pre_b1 = (const float*)d_in[3];
  const float* pre_w2 = (const float*)d_in[4];
  const float* pre_b2 = (const float*)d_in[5];
  const float* skip   = (const float*)d_in[6];
  const float* wl0 = (const float*)d_in[7],  *bl0 = (const float*)d_in[8],  *wr0 = (const float*)d_in[9];
  const float* wl1 = (const float*)d_in[10], *bl1 = (const float*)d_in[11], *wr1 = (const float*)d_in[12];
  const float* wl2 = (const float*)d_in[13], *bl2 = (const float*)d_in[14], *wr2 = (const float*)d_in[15];
  const float* pw1 = (const float*)d_in[16], *pb1 = (const float*)d_in[17];
  const float* pw2 = (const float*)d_in[18], *pb2 = (const float*)d_in[19];
  const float* pw3 = (const float*)d_in[20], *pb3 = (const float*)d_in[21];
  const float* pw4 = (const float*)d_in[22], *pb4 = (const float*)d_in[23];
  float* out = (float*)d_out;

  const int N = NN, E = NE;

  // workspace carve-up
  char* ws = (char*)d_ws;
  size_t pos = 0;
  auto alloc = [&](size_t bytes) {
    char* p = ws + pos;
    pos += (bytes + 255) & ~(size_t)255;
    return (void*)p;
  };
  int*      gbcnt = (int*)alloc((size_t)NB * 4);
  int*      boff  = (int*)alloc((size_t)(NB + 1) * 4);
  int*      gcur  = (int*)alloc((size_t)NB * 4);
  unsigned* ebuf  = (unsigned*)alloc((size_t)E * 4);
  int*      offs  = (int*)alloc((size_t)(N + 1) * 4);
  float*    invd  = (float*)alloc((size_t)N * 4);
  int*      csr   = (int*)alloc((size_t)E * 4);
  unsigned short* wbuf = (unsigned short*)alloc((size_t)15 * 8192 * 2);
  const size_t PB = (size_t)N * 128 * 2;   // interleaved hi|lo rows, bytes
  unsigned short* x  = (unsigned short*)alloc(PB);
  unsigned short* h0 = (unsigned short*)alloc(PB);
  unsigned short* h1 = (unsigned short*)alloc(PB);
  unsigned short* h2 = (unsigned short*)alloc(PB);
  unsigned short* m0 = (unsigned short*)alloc(PB);
  unsigned short* m1 = (unsigned short*)alloc(PB);
  float* sv = (float*)alloc(256 * 4);

  hipMemsetAsync(gbcnt, 0, (size_t)NB * 4, stream);
  hipMemsetAsync(sv, 0, 256 * 4, stream);

  // ---- W pre-pack: slots 0..14 ----
  {
    WPrepArgs P;
    const float* wsrc[15] = {
      pre_w1, pre_w1 + 64 * 64,
      pre_w2,
      wl0, wr0,
      wl1, wl1 + 64 * 64, wr1, wr1 + 64 * 64,
      wl2, wl2 + 64 * 64, wl2 + 128 * 64,
      wr2, wr2 + 64 * 64, wr2 + 128 * 64
    };
    int gi[15] = {-1, -1, -1, 0, 0, 3, 4, 3, 4, 6, 7, 8, 6, 7, 8};
    for (int i = 0; i < 15; ++i) { P.w[i] = wsrc[i]; P.gidx[i] = gi[i]; }
    P.skip = skip; P.wbuf = wbuf;
    k_wprep<<<15, 256, 0, stream>>>(P);
  }

  const int* e_src = ei;
  const int* e_dst = ei + E;
  const int EGRID = (E + 4095) / 4096;   // 196
  k_bhist<<<EGRID, 256, 0, stream>>>(e_dst, gbcnt);
  k_bscan<<<1, 256, 0, stream>>>(gbcnt, boff, gcur, offs);
  k_bscatter<<<EGRID, 256, 0, stream>>>(e_src, e_dst, gcur, ebuf);
  k_bbuild<<<NB, 256, 0, stream>>>(ebuf, boff, offs, invd, csr);

  const int LGRID = (N + 63) / 64;   // 782

  // fused pre-MLP -> x (+colsum sv[0:64])
  {
    PreArgs P;
    P.nf = nf; P.b1 = pre_b1; P.b2 = pre_b2;
    P.wbuf = wbuf; P.outx = x; P.colsum = sv; P.n = N;
    k_pre<<<LGRID, 1024, 0, stream>>>(P);
  }

  auto layer = [&](const unsigned short* gfeat, unsigned short* mean_out,
                   int nsrc,
                   const unsigned short* a1, const unsigned short* a2,
                   const unsigned short* a3, const unsigned short* a4,
                   const unsigned short* a5,
                   int s0, int s1, int s2, int s3, int s4, int s5,
                   const float* bias, unsigned short* outp, float* colsum) {
    LayerArgs A;
    A.gfeat = gfeat; A.offs = offs; A.csr = csr; A.invd = invd;
    A.mean_out = mean_out;
    A.asrc[0] = nullptr; A.asrc[1] = a1; A.asrc[2] = a2;
    A.asrc[3] = a3; A.asrc[4] = a4; A.asrc[5] = a5;
    A.wslot[0] = s0; A.wslot[1] = s1; A.wslot[2] = s2;
    A.wslot[3] = s3; A.wslot[4] = s4; A.wslot[5] = s5;
    A.nsrc = nsrc; A.bias = bias; A.wbuf = wbuf;
    A.outp = outp; A.colsum = colsum; A.n = N;
    k_layer<<<LGRID, 1024, 0, stream>>>(A);
  };

  // layer 0: LDS mean=agg(x)->m0(slot3); x(slot4)
  layer(x, m0, 2, x, nullptr, nullptr, nullptr, nullptr,
        3, 4, 0, 0, 0, 0, bl0, h0, sv + 64);
  // layer 1: LDS mean=agg(h0)->m1(slot6); m0(5), x(7), h0(8)
  layer(h0, m1, 4, m0, x, h0, nullptr, nullptr,
        6, 5, 7, 8, 0, 0, bl1, h1, sv + 128);
  // layer 2: LDS mean=agg(h1) (slot11, not persisted); m0(9), m1(10), x(12), h0(13), h1(14)
  layer(h1, nullptr, 6, m0, m1, x, h0, h1,
        11, 9, 10, 12, 13, 14, bl2, h2, sv + 192);

  // post-MLP on the fused column sums
  k_post<<<1, 256, 0, stream>>>(sv, pw1, pb1, pw2, pb2, pw3, pb3, pw4, pb4, out);
}